// Round 5
// baseline (131.431 us; speedup 1.0000x reference)
//
#include <hip/hip_runtime.h>

// WaveletProcessor: 4x [Conv1d(64,64,k) -> ReLU -> Conv1d(64,64,1)], softmax-weighted sum.
// Device buffers are float32. Compute: bf16 MFMA (32x32x16), fp32 accum.
// Round 5: 32x32x16 MFMA for conv1+conv2. Halves per-lane weight fetch, ~15% fewer
// MFMA cycles, 4x fewer weight-load instructions. conv2 consumes ReLU(conv1) from
// registers via cvt_pk + cross-half shfl repack (D-layout -> B-layout). One barrier.

constexpr int Bn = 32, Ln = 8192;
constexpr int NT = 256;          // length-tile per workgroup (4 waves x 64)
constexpr int HALO = 4;          // max pad
constexpr int XROWS = NT + 2 * HALO;   // 264
constexpr int RS = 72;           // LDS row stride in ushorts (144B)

using bf16x8 = __attribute__((ext_vector_type(8))) __bf16;
using f32x4  = __attribute__((ext_vector_type(4))) float;
using f32x16 = __attribute__((ext_vector_type(16))) float;
using u16x8  = __attribute__((ext_vector_type(8))) unsigned short;
using u32x4  = __attribute__((ext_vector_type(4))) unsigned int;

struct Ptrs {
    const float* x;
    const float* rw;
    const float* w1[4];
    const float* b1[4];
    const float* w2[4];
    const float* b2[4];
};

__device__ __forceinline__ unsigned short f2bf(float f) {
    __bf16 h = (__bf16)f;                       // native cvt, RNE
    return __builtin_bit_cast(unsigned short, h);
}
__device__ __forceinline__ unsigned pack2bf(float lo, float hi) {
    return ((unsigned)f2bf(hi) << 16) | (unsigned)f2bf(lo);
}

__device__ __forceinline__ void mfma32(f32x16& c, bf16x8 a, bf16x8 b) {
    c = __builtin_amdgcn_mfma_f32_32x32x16_bf16(a, b, c, 0, 0, 0);
}

// ---------------- prep: softmax + weight fragment pre-transposition ----------------
// d_ws: [0..3] float softmax w; [4..67] float fused bias (sum_i w_i*b2_i);
// at byte 512: bf16 fragment blocks of 512 elems (1KB) in 32x32x16 A-layout:
//   elem = lane*8 + j; A[m][k]: m = mt*32+(lane&31), k(within 16) = (lane>>5)*8 + j.
//   F1: branch bases {0,24,48,88} blocks; block-in-branch = dk*8 + kb*2 + mt
//       (ci = kb*16 + (lane>>5)*8 + j), value = W1[co][ci][dk].
//   F2: block 160 + br*8 + kb*2 + mt, value = w[br] * W2[co][ci].
__global__ void prep_kernel(Ptrs p, unsigned short* __restrict__ frag, float* __restrict__ hdr) {
    int tid = threadIdx.x;
    float v0 = p.rw[0], v1 = p.rw[1], v2 = p.rw[2], v3 = p.rw[3];
    float m = fmaxf(fmaxf(v0, v1), fmaxf(v2, v3));
    float e0 = expf(v0 - m), e1 = expf(v1 - m), e2 = expf(v2 - m), e3 = expf(v3 - m);
    float s = e0 + e1 + e2 + e3;
    float w[4] = {e0 / s, e1 / s, e2 / s, e3 / s};

    if (blockIdx.x == 0) {
        if (tid < 4) hdr[tid] = w[tid];
        if (tid < 64) {
            float fb = 0.f;
            #pragma unroll
            for (int i = 0; i < 4; i++) fb += w[i] * p.b2[i][tid];
            hdr[4 + tid] = fb;
        }
    }

    const int kk[4] = {3, 3, 5, 9};
    const int f1blocks[4] = {24, 24, 40, 72};   // k*8 blocks per branch

    for (int idx = blockIdx.x * blockDim.x + tid; idx < 192 * 512; idx += gridDim.x * blockDim.x) {
        int blk = idx >> 9;
        int e = idx & 511;
        int lane = e >> 3, j = e & 7;
        unsigned short val;
        if (blk < 160) {
            int br = 0, rem = blk;
            while (rem >= f1blocks[br]) { rem -= f1blocks[br]; br++; }
            int dk = rem >> 3, kb = (rem >> 1) & 3, mt = rem & 1;
            int co = mt * 32 + (lane & 31);
            int ci = kb * 16 + (lane >> 5) * 8 + j;
            val = f2bf(p.w1[br][(co * 64 + ci) * kk[br] + dk]);
        } else {
            int rem = blk - 160;
            int br = rem >> 3, kb = (rem >> 1) & 3, mt = rem & 1;
            int co = mt * 32 + (lane & 31);
            int ci = kb * 16 + (lane >> 5) * 8 + j;
            val = f2bf(w[br] * p.w2[br][co * 64 + ci]);
        }
        frag[idx] = val;
    }
}

// ---------------- main kernel ----------------
template <int KK, int PP>
__device__ __forceinline__ void do_branch(const unsigned short* __restrict__ frag1,
                                          const unsigned short* __restrict__ frag2,
                                          const float* __restrict__ b1,
                                          const unsigned short* xs,
                                          int lane, int wl0, f32x16 (&fused)[2][2]) {
    int n = lane & 31;
    int hi = lane >> 5;
    bool ishi = hi != 0;

    // conv1 accumulators init to b1[co]; reg r of tile mt: co = mt*32 + (r&3)+8*(r>>2)+4*hi
    f32x16 acc[2][2];
    #pragma unroll
    for (int mt = 0; mt < 2; mt++) {
        f32x16 bi;
        #pragma unroll
        for (int g = 0; g < 4; g++) {
            f32x4 v = *(const f32x4*)&b1[mt * 32 + g * 8 + hi * 4];
            #pragma unroll
            for (int i = 0; i < 4; i++) bi[4 * g + i] = v[i];
        }
        acc[mt][0] = bi; acc[mt][1] = bi;
    }

    #pragma unroll
    for (int dk = 0; dk < KK; dk++) {
        // B-fragments from LDS: 16B at [row][kb*16 + hi*8]
        bf16x8 bfr[2][4];
        #pragma unroll
        for (int nl = 0; nl < 2; nl++) {
            int row = wl0 + nl * 32 + n + (HALO - PP) + dk;
            #pragma unroll
            for (int kb = 0; kb < 4; kb++)
                bfr[nl][kb] = __builtin_bit_cast(bf16x8, *(const u16x8*)&xs[row * RS + kb * 16 + hi * 8]);
        }
        // A-fragments (weights) from global
        const unsigned short* fp = frag1 + (size_t)(dk * 8) * 512 + lane * 8;
        #pragma unroll
        for (int kb = 0; kb < 4; kb++) {
            #pragma unroll
            for (int mt = 0; mt < 2; mt++) {
                bf16x8 afr = __builtin_bit_cast(bf16x8, *(const u16x8*)(fp + (size_t)(kb * 2 + mt) * 512));
                #pragma unroll
                for (int nl = 0; nl < 2; nl++)
                    mfma32(acc[mt][nl], afr, bfr[nl][kb]);
            }
        }
    }

    // conv2 (1x1) from registers. ReLU + pack pairs, cross-half shfl repack:
    // packed reg (mt,p) holds H rows 32*mt + {0,2,8,10,16,18,24,26}[p] + 4*hi (pair).
    // B-frag for kb: q0=[a0_lo,b0_lo] q1=[a1_lo,b1_lo] q2=[a0_hi,b0_hi] q3=[a1_hi,b1_hi]
    // with a=pk[kb>>1][(kb&1)*4 + {0,1}], b=pk[kb>>1][(kb&1)*4 + {2,3}].
    #pragma unroll
    for (int nl = 0; nl < 2; nl++) {
        unsigned pk[2][8];
        #pragma unroll
        for (int mt = 0; mt < 2; mt++)
            #pragma unroll
            for (int pp = 0; pp < 8; pp++)
                pk[mt][pp] = pack2bf(fmaxf(acc[mt][nl][2 * pp], 0.f),
                                     fmaxf(acc[mt][nl][2 * pp + 1], 0.f));
        #pragma unroll
        for (int kb = 0; kb < 4; kb++) {
            int mq = kb >> 1, pb = (kb & 1) * 4;
            unsigned a0 = pk[mq][pb + 0], a1 = pk[mq][pb + 1];
            unsigned b0 = pk[mq][pb + 2], b1q = pk[mq][pb + 3];
            unsigned xa0 = __shfl_xor((int)a0, 32);
            unsigned xa1 = __shfl_xor((int)a1, 32);
            unsigned xb0 = __shfl_xor((int)b0, 32);
            unsigned xb1 = __shfl_xor((int)b1q, 32);
            u32x4 q;
            q[0] = ishi ? xb0 : a0;
            q[1] = ishi ? xb1 : a1;
            q[2] = ishi ? b0 : xa0;
            q[3] = ishi ? b1q : xa1;
            bf16x8 bq = __builtin_bit_cast(bf16x8, q);
            const unsigned short* fp2 = frag2 + lane * 8;
            #pragma unroll
            for (int mt2 = 0; mt2 < 2; mt2++) {
                bf16x8 afr = __builtin_bit_cast(bf16x8, *(const u16x8*)(fp2 + (size_t)(kb * 2 + mt2) * 512));
                mfma32(fused[mt2][nl], afr, bq);
            }
        }
    }
}

__global__ __launch_bounds__(256, 2) void wavelet_main(Ptrs p,
                                                       const unsigned short* __restrict__ frag,
                                                       const float* __restrict__ hdr,
                                                       float* __restrict__ out) {
    __shared__ unsigned short xs[XROWS * RS];   // 38016 B

    int tid = threadIdx.x;
    int b = blockIdx.x >> 5;           // 32 tiles per batch
    int t0 = (blockIdx.x & 31) * NT;

    // stage x tile (+halo) into LDS as bf16, zero-padded at batch edges
    {
        int c0 = (tid & 7) * 8;
        int rbase = tid >> 3;          // 0..31
        #pragma unroll
        for (int it = 0; it < 9; it++) {
            int rr = it * 32 + rbase;
            if (rr < XROWS) {
                int l = t0 + rr - HALO;
                u16x8 v = {0, 0, 0, 0, 0, 0, 0, 0};
                if (l >= 0 && l < Ln) {
                    const float* src = &p.x[((size_t)b * Ln + l) * 64 + c0];
                    f32x4 a0 = *(const f32x4*)src;
                    f32x4 a1 = *(const f32x4*)(src + 4);
                    #pragma unroll
                    for (int r = 0; r < 4; r++) { v[r] = f2bf(a0[r]); v[4 + r] = f2bf(a1[r]); }
                }
                *(u16x8*)&xs[rr * RS + c0] = v;
            }
        }
    }

    int lane = tid & 63;
    int wl0 = (tid >> 6) * 64;   // each wave owns a 64-wide L-chunk
    int hi = lane >> 5;

    // fused accumulator init = sum_i w_i * b2_i[co]
    f32x16 fused[2][2];
    #pragma unroll
    for (int mt = 0; mt < 2; mt++) {
        f32x16 fi;
        #pragma unroll
        for (int g = 0; g < 4; g++) {
            f32x4 v = *(const f32x4*)&hdr[4 + mt * 32 + g * 8 + hi * 4];
            #pragma unroll
            for (int i = 0; i < 4; i++) fi[4 * g + i] = v[i];
        }
        fused[mt][0] = fi; fused[mt][1] = fi;
    }

    __syncthreads();   // xs ready — the only barrier

    do_branch<3, 1>(frag + (size_t)0 * 512,  frag + (size_t)(160 + 0)  * 512, p.b1[0], xs, lane, wl0, fused);
    do_branch<3, 1>(frag + (size_t)24 * 512, frag + (size_t)(160 + 8)  * 512, p.b1[1], xs, lane, wl0, fused);
    do_branch<5, 2>(frag + (size_t)48 * 512, frag + (size_t)(160 + 16) * 512, p.b1[2], xs, lane, wl0, fused);
    do_branch<9, 4>(frag + (size_t)88 * 512, frag + (size_t)(160 + 24) * 512, p.b1[3], xs, lane, wl0, fused);

    // write output: out[b][l][c], c = mt*32 + g*8 + hi*4 + i, l = t0+wl0+nl*32+n
    int n = lane & 31;
    #pragma unroll
    for (int mt = 0; mt < 2; mt++) {
        #pragma unroll
        for (int nl = 0; nl < 2; nl++) {
            int l = t0 + wl0 + nl * 32 + n;
            #pragma unroll
            for (int g = 0; g < 4; g++) {
                f32x4 v;
                #pragma unroll
                for (int i = 0; i < 4; i++) v[i] = fused[mt][nl][4 * g + i];
                *(f32x4*)&out[((size_t)b * Ln + l) * 64 + mt * 32 + g * 8 + hi * 4] = v;
            }
        }
    }
}

extern "C" void kernel_launch(void* const* d_in, const int* in_sizes, int n_in,
                              void* d_out, int out_size, void* d_ws, size_t ws_size,
                              hipStream_t stream) {
    Ptrs p;
    p.x  = (const float*)d_in[0];
    p.rw = (const float*)d_in[1];
    for (int i = 0; i < 4; i++) {
        p.w1[i] = (const float*)d_in[2 + 4 * i];
        p.b1[i] = (const float*)d_in[3 + 4 * i];
        p.w2[i] = (const float*)d_in[4 + 4 * i];
        p.b2[i] = (const float*)d_in[5 + 4 * i];
    }
    float* hdr = (float*)d_ws;
    unsigned short* frag = (unsigned short*)((char*)d_ws + 512);

    hipLaunchKernelGGL(prep_kernel, dim3(96), dim3(256), 0, stream, p, frag, hdr);
    hipLaunchKernelGGL(wavelet_main, dim3(Bn * (Ln / NT)), dim3(256), 0, stream, p, frag, hdr,
                       (float*)d_out);
}